// Round 7
// baseline (3122.411 us; speedup 1.0000x reference)
//
#include <hip/hip_runtime.h>
#include <math.h>

#define N_V 5000
#define N_F 10000
#define NNZ 480000
#define LAYERS 30

typedef short short8 __attribute__((ext_vector_type(8)));
typedef float f32x4 __attribute__((ext_vector_type(4)));
union BFu { uint4 u; short8 s8; short s[8]; };

__device__ __forceinline__ float eluf(float x){ return x>0.f ? x : expm1f(x); }
__device__ __forceinline__ short f2bf(float f){
  unsigned u = __float_as_uint(f);
  unsigned r = (u + 0x7fffu + ((u>>16)&1u)) >> 16;
  return (short)r;
}

// ---------------- CSR build ----------------
__global__ void hist_both(const int* __restrict__ Di_rows, const int* __restrict__ DiA_rows,
                          int* __restrict__ Di_cur, int* __restrict__ DA_cur){
  int e = blockIdx.x*256 + threadIdx.x;
  if(e < NNZ){
    atomicAdd(&Di_cur[Di_rows[e]], 1);
    atomicAdd(&DA_cur[DiA_rows[e]], 1);
  }
}

__global__ void chunkscan(const int* __restrict__ Di_cur, int* __restrict__ Di_ptr,
                          const int* __restrict__ DA_cur, int* __restrict__ DA_ptr,
                          int* __restrict__ bsumDi, int* __restrict__ bsumDA){
  __shared__ int ish[256];
  int b = blockIdx.x, tid = threadIdx.x;
  const int nchDi = 157;
  const int* hist; int* optr; int n; int cb; int* bs;
  if(b < nchDi){ hist=Di_cur; optr=Di_ptr; n=40000; cb=b; bs=bsumDi; }
  else { hist=DA_cur; optr=DA_ptr; n=20000; cb=b-nchDi; bs=bsumDA; }
  int i = cb*256 + tid;
  int v = (i<n)? hist[i] : 0;
  ish[tid]=v; __syncthreads();
  for(int off=1; off<256; off<<=1){
    int t = (tid>=off)? ish[tid-off] : 0;
    __syncthreads(); ish[tid]+=t; __syncthreads();
  }
  if(i<n) optr[i] = ish[tid]-v;
  if(tid==255) bs[cb]=ish[255];
}

__global__ void topscan(int* __restrict__ bsumDi, int* __restrict__ bsumDA){
  __shared__ int ish[256];
  int tid=threadIdx.x;
  int* bs = (blockIdx.x==0) ? bsumDi : bsumDA;
  int n  = (blockIdx.x==0) ? 157 : 79;
  int v = (tid<n)? bs[tid] : 0;
  ish[tid]=v; __syncthreads();
  for(int off=1; off<256; off<<=1){
    int t=(tid>=off)? ish[tid-off]:0;
    __syncthreads(); ish[tid]+=t; __syncthreads();
  }
  if(tid<n) bs[tid]=ish[tid]-v;
}

__global__ void addback(int* __restrict__ Di_ptr, int* __restrict__ Di_cur,
                        const int* __restrict__ bsumDi,
                        int* __restrict__ DA_ptr, int* __restrict__ DA_cur,
                        const int* __restrict__ bsumDA){
  int stride = gridDim.x*256;
  int base = blockIdx.x*256 + threadIdx.x;
  for(int i=base;i<40000;i+=stride){ int v=Di_ptr[i]+bsumDi[i>>8]; Di_ptr[i]=v; Di_cur[i]=v; }
  for(int i=base;i<20000;i+=stride){ int v=DA_ptr[i]+bsumDA[i>>8]; DA_ptr[i]=v; DA_cur[i]=v; }
  if(base==0){ Di_ptr[40000]=NNZ; DA_ptr[20000]=NNZ; }
}

__global__ void scatter_perm(const int* __restrict__ Di_rows, int* __restrict__ Di_cur,
                             int* __restrict__ Di_perm,
                             const int* __restrict__ DiA_rows, int* __restrict__ DA_cur,
                             int* __restrict__ DA_perm){
  int e = blockIdx.x*256 + threadIdx.x;
  if(e >= NNZ) return;
  int pos = atomicAdd(&Di_cur[Di_rows[e]], 1);
  Di_perm[pos] = e;
  pos = atomicAdd(&DA_cur[DiA_rows[e]], 1);
  DA_perm[pos] = e;
}

__global__ void gather_pairs(const int* __restrict__ Di_perm, const int* __restrict__ Di_cols,
                             const float* __restrict__ Di_vals, float2* __restrict__ Di_pairs,
                             const int* __restrict__ DA_perm, const int* __restrict__ DiA_cols,
                             const float* __restrict__ DiA_vals, float2* __restrict__ DA_pairs){
  int p = blockIdx.x*256 + threadIdx.x;
  if(p >= NNZ) return;
  int e = Di_perm[p];
  Di_pairs[p] = make_float2(__int_as_float(Di_cols[e]), Di_vals[e]);
  e = DA_perm[p];
  DA_pairs[p] = make_float2(__int_as_float(DiA_cols[e]), DiA_vals[e]);
}

// ---------------- weight convert: Wt[(2i+m)*128 + n][k] = bf16(W_m[i][k][n]) ----
__global__ void wconv(const float* __restrict__ W0, const float* __restrict__ Wl1,
                      short* __restrict__ Wt){
  int b = blockIdx.x;            // 60 = i*2+m
  int i = b>>1, m = b&1;
  const float* W = (m ? Wl1 : W0) + (size_t)i*32768;
  short* out = Wt + (size_t)b*32768;
  int k = threadIdx.x;           // 256
  for(int n=0;n<128;++n)
    out[n*256 + k] = f2bf(W[k*128 + n]);
}

// ---------------- conv1 (+ elu stats) + odd-bias precompute ----
__global__ void conv1_kernel(const float* __restrict__ in, const float* __restrict__ W_in,
                             const float* __restrict__ b_in,
                             const float* __restrict__ be0, const float* __restrict__ W0,
                             const float* __restrict__ be1, const float* __restrict__ Wl1,
                             float* __restrict__ v_raw, float* __restrict__ elu_v,
                             float* __restrict__ st1, float* __restrict__ oddb){
  __shared__ float pool[256];
  int tid = threadIdx.x;
  int stride = gridDim.x*256;
  float ls=0.f, ls2=0.f;
  for(int idx = blockIdx.x*256+tid; idx < N_V*128; idx += stride){
    int n = idx>>7, c = idx&127;
    float v = b_in[c] + in[n*3]*W_in[c] + in[n*3+1]*W_in[128+c] + in[n*3+2]*W_in[256+c];
    v_raw[idx] = v;
    float ev = eluf(v);
    elu_v[idx] = ev;
    ls += ev; ls2 += ev*ev;
  }
  int ch = tid & 127;
  pool[tid]=ls; __syncthreads();
  if(tid<128) atomicAdd(&st1[ch], pool[tid]+pool[tid+128]);
  __syncthreads();
  pool[tid]=ls2; __syncthreads();
  if(tid<128) atomicAdd(&st1[256+ch], pool[tid]+pool[tid+128]);
  for(int item = blockIdx.x*256+tid; item < LAYERS*2*128; item += stride){
    int i = item >> 8;
    int m = (item >> 7) & 1;
    int j = item & 127;
    const float* be = m ? be1 : be0;
    const float* W  = m ? Wl1 : W0;
    const float* wp = W + (size_t)i*32768 + 128*128 + j;
    const float* bp = be + i*256 + 128;
    float s = 0.f;
    for(int k=0;k<128;++k) s += bp[k]*wp[k*128];
    oddb[item] = s;
  }
}

// ---------------- SpMM: one wave per row, software-pipelined edge stream ----
__global__ __launch_bounds__(256) void spmm_bn(
    const int* __restrict__ ptr, const float2* __restrict__ pairs,
    const float* __restrict__ x, float* __restrict__ y, int nrows,
    float* __restrict__ stslot){
  __shared__ float pool[128];
  int tid = threadIdx.x;
  int w = tid>>6, lane = tid&63;
  int j = lane&31, eh = lane>>5;
  float ls=0.f, ls2=0.f;
  for(int row = blockIdx.x*4 + w; row < nrows; row += gridDim.x*4){
    int s = ptr[row], e = ptr[row+1];
    float acc = 0.f;
    int i = s + eh;
    float2 p = (i < e) ? pairs[i] : make_float2(0.f, 0.f);
    while(i < e){
      int inext = i + 2;
      float2 pn = (inext < e) ? pairs[inext] : make_float2(0.f, 0.f);
      acc += p.y * x[(__float_as_int(p.x)<<5) + j];
      p = pn; i = inext;
    }
    acc += __shfl_xor(acc, 32);
    if(eh==0){
      y[(row<<5) + j] = acc;
      ls += acc; ls2 += acc*acc;
    }
  }
  int ch = (w<<5) | j;
  if(eh==0) pool[ch] = ls;
  __syncthreads();
  if(tid<128) atomicAdd(&stslot[128+tid], pool[tid]);
  __syncthreads();
  if(eh==0) pool[ch] = ls2;
  __syncthreads();
  if(tid<128) atomicAdd(&stslot[384+tid], pool[tid]);
}

// ---------------- MFMA GEMM (K templated -> fully unrolled main loop) ----
// Block 256 thr = 4 waves. Tile 16 rows x 128 cols: wave w -> cols w*32..w*32+31.
// A frag: m=lane&15, k=quad*8+j (fp32 global load + BN + bf16 cvt, no LDS).
// B frag: n=lane&15, k=quad*8+j (16B load from bf16 transposed Wt[n][k], stride 256).
// D frag: col=lane&15, row=quad*4+reg.
template<int K>
__global__ __launch_bounds__(256) void gemm_mfma(
    const float* __restrict__ A0, const float* __restrict__ A1,
    const float* __restrict__ st, float invM,
    const float* __restrict__ g, const float* __restrict__ be,
    const short* __restrict__ Wt, const float* __restrict__ bias,
    const float* __restrict__ bias2, const float* __restrict__ resid,
    float* __restrict__ out_raw, float* __restrict__ out_elu,
    float* __restrict__ stE, float* __restrict__ stR, int M)
{
  __shared__ float ab[K], bb[K];
  int tid = threadIdx.x;
  if(tid < K){
    float mean = st[tid]*invM;
    float var  = fmaxf(st[256+tid]*invM - mean*mean, 0.f);
    float aa   = g[tid]*rsqrtf(var + 1e-5f);
    ab[tid] = aa; bb[tid] = be[tid] - mean*aa;
  }
  __syncthreads();

  int wave = tid>>6, lane = tid&63;
  int ln = lane&15, q = lane>>4;
  int r0 = blockIdx.x*16;
  int c0 = wave*32;
  int kq = q*8;
  int arow = r0 + ln;
  bool aok = arow < M;

  f32x4 acc[2] = {};
  #pragma unroll
  for(int kb=0; kb<K; kb+=32){
    const float* src = (kb >= 128) ? A1 : A0;          // compile-time after unroll
    int kk = ((kb >= 128) ? kb-128 : kb) + kq;
    int kg = kb + kq;
    float av[8];
    if(aok){
      float4 x0 = *(const float4*)&src[arow*128 + kk];
      float4 x1 = *(const float4*)&src[arow*128 + kk + 4];
      av[0]=x0.x; av[1]=x0.y; av[2]=x0.z; av[3]=x0.w;
      av[4]=x1.x; av[5]=x1.y; av[6]=x1.z; av[7]=x1.w;
    } else {
      #pragma unroll
      for(int j2=0;j2<8;++j2) av[j2]=0.f;
    }
    BFu af;
    #pragma unroll
    for(int j2=0;j2<8;++j2) af.s[j2] = f2bf(fmaf(av[j2], ab[kg+j2], bb[kg+j2]));
    #pragma unroll
    for(int nb=0;nb<2;++nb){
      int n = c0 + nb*16 + ln;
      BFu bfv; bfv.u = *(const uint4*)&Wt[n*256 + kb + kq];
      acc[nb] = __builtin_amdgcn_mfma_f32_16x16x32_bf16(af.s8, bfv.s8, acc[nb], 0, 0, 0);
    }
  }

  int rbase = r0 + q*4;
  bool wantR = (stR != nullptr);
  #pragma unroll
  for(int nb=0;nb<2;++nb){
    int col = c0 + nb*16 + ln;
    float bsum = bias[col] + (bias2 ? bias2[col] : 0.f);
    float s=0.f, s2=0.f, rs=0.f, rs2=0.f;
    #pragma unroll
    for(int reg=0;reg<4;++reg){
      int row = rbase + reg;
      bool ok = row < M;
      float v = acc[nb][reg] + bsum;
      if(resid && ok) v += resid[row*128 + col];
      float ve = eluf(v);
      if(ok){
        if(out_raw) out_raw[row*128 + col] = v;
        if(out_elu) out_elu[row*128 + col] = ve;
        s += ve; s2 += ve*ve;
        if(wantR){ rs += v; rs2 += v*v; }
      }
    }
    s  += __shfl_xor(s, 16);  s  += __shfl_xor(s, 32);
    s2 += __shfl_xor(s2, 16); s2 += __shfl_xor(s2, 32);
    if(wantR){
      rs  += __shfl_xor(rs, 16);  rs  += __shfl_xor(rs, 32);
      rs2 += __shfl_xor(rs2, 16); rs2 += __shfl_xor(rs2, 32);
    }
    if(q==0){
      if(stE){ atomicAdd(&stE[col], s); atomicAdd(&stE[256+col], s2); }
      if(wantR){ atomicAdd(&stR[col], rs); atomicAdd(&stR[256+col], rs2); }
    }
  }
}

// ---------------- final: BN(v) @ W_out + b_out, elu ------------------
__global__ void final_kernel(const float* __restrict__ v_raw, const float* __restrict__ st,
                             const float* __restrict__ g2, const float* __restrict__ be2,
                             const float* __restrict__ W_out, const float* __restrict__ b_out,
                             float* __restrict__ out){
  __shared__ float pool[256];
  int tid = threadIdx.x; int half = tid>>7, k = tid&127;
  float mean = st[k]*(1.f/N_V);
  float var = fmaxf(st[256+k]*(1.f/N_V) - mean*mean, 0.f);
  float aa = g2[k]*rsqrtf(var+1e-5f);
  float scale = aa*W_out[k];
  float cons = (be2[k]-mean*aa)*W_out[k];
  int r = blockIdx.x*2 + half;
  float val = v_raw[r*128+k]*scale + cons;
  pool[tid]=val; __syncthreads();
  for(int s=64;s>=1;s>>=1){ if(k<s) pool[tid]+=pool[tid+s]; __syncthreads(); }
  if(k==0) out[r] = eluf(pool[tid] + b_out[0]);
}

extern "C" void kernel_launch(void* const* d_in, const int* in_sizes, int n_in,
                              void* d_out, int out_size, void* d_ws, size_t ws_size,
                              hipStream_t stream){
  const float* inputs  = (const float*)d_in[0];
  const int*   Di_rows = (const int*)d_in[2];
  const int*   Di_cols = (const int*)d_in[3];
  const float* Di_vals = (const float*)d_in[4];
  const int*   DiA_rows= (const int*)d_in[5];
  const int*   DiA_cols= (const int*)d_in[6];
  const float* DiA_vals= (const float*)d_in[7];
  const float* W_in = (const float*)d_in[8];  const float* b_in = (const float*)d_in[9];
  const float* g0  = (const float*)d_in[10];  const float* be0 = (const float*)d_in[11];
  const float* W0  = (const float*)d_in[12];  const float* b0  = (const float*)d_in[13];
  const float* g1  = (const float*)d_in[14];  const float* be1 = (const float*)d_in[15];
  const float* Wl1 = (const float*)d_in[16];  const float* bl1 = (const float*)d_in[17];
  const float* g2  = (const float*)d_in[18];  const float* be2 = (const float*)d_in[19];
  const float* W_out = (const float*)d_in[20]; const float* b_out = (const float*)d_in[21];

  float* ws = (float*)d_ws;
  float* v_raw = ws;                       // 640000
  float* elu_v = ws + 640000;              // 640000
  float* elu_f = ws + 1280000;             // 1280000
  float* Dv    = ws + 2560000;             // 1280000 (elu_x1 alias on odd layers)
  float* DAf   = ws + 3840000;             // 640000
  float* st    = ws + 4480000;             // 64*512
  float* oddb  = ws + 4512768;             // 7680
  int* Di_ptr  = (int*)(ws + 4520448);     // 40001
  int* DA_ptr  = (int*)(ws + 4560449);     // 20001
  int* Di_cur  = (int*)(ws + 4580450);     // 40000 } one memset
  int* DA_cur  = (int*)(ws + 4620450);     // 20000 }
  float2* Di_pairs = (float2*)(ws + 4640450);  // 960000 floats
  float2* DA_pairs = (float2*)(ws + 5600450);  // 960000 floats
  int* bsumDi  = (int*)(ws + 6560450);     // 256
  int* bsumDA  = (int*)(ws + 6560706);     // 128
  int* Di_perm = (int*)(ws + 6560834);     // 480000  } perm dead after gather;
  int* DA_perm = (int*)(ws + 7040834);     // 480000  } Wt aliases this region
  short* Wt    = (short*)(ws + 6560834);   // 60*32768 shorts = 983040 floats

  hipMemsetAsync(st, 0, (size_t)64*512*sizeof(float), stream);
  hipMemsetAsync(elu_f, 0, (size_t)1280000*sizeof(float), stream);
  hipMemsetAsync(Di_cur, 0, (size_t)60000*sizeof(int), stream);

  hist_both<<<1875, 256, 0, stream>>>(Di_rows, DiA_rows, Di_cur, DA_cur);
  chunkscan<<<236, 256, 0, stream>>>(Di_cur, Di_ptr, DA_cur, DA_ptr, bsumDi, bsumDA);
  topscan<<<2, 256, 0, stream>>>(bsumDi, bsumDA);
  addback<<<236, 256, 0, stream>>>(Di_ptr, Di_cur, bsumDi, DA_ptr, DA_cur, bsumDA);
  scatter_perm<<<1875, 256, 0, stream>>>(Di_rows, Di_cur, Di_perm, DiA_rows, DA_cur, DA_perm);
  gather_pairs<<<1875, 256, 0, stream>>>(Di_perm, Di_cols, Di_vals, Di_pairs,
                                         DA_perm, DiA_cols, DiA_vals, DA_pairs);
  wconv<<<60, 256, 0, stream>>>(W0, Wl1, Wt);   // after gather: Wt aliases perm space
  conv1_kernel<<<640, 256, 0, stream>>>(inputs, W_in, b_in, be0, W0, be1, Wl1,
                                        v_raw, elu_v, st + 512, oddb);

  for(int i=0;i<LAYERS;++i){
    if((i&1)==0){
      float* S0  = st + (size_t)(2*i)*512;
      float* S1b = st + (size_t)(2*i+1)*512;
      spmm_bn<<<2048, 256, 0, stream>>>(Di_ptr, Di_pairs, elu_v, Dv, 40000, S0);
      gemm_mfma<256><<<625, 256, 0, stream>>>(elu_f, Dv, S0, 1.f/N_F, g0+i*256, be0+i*256,
                                         Wt + (size_t)(2*i)*32768, b0+i*128, nullptr,
                                         nullptr, nullptr, elu_f,
                                         st+(size_t)(2*(i+2))*512, nullptr, N_F);
      spmm_bn<<<1024, 256, 0, stream>>>(DA_ptr, DA_pairs, elu_f, DAf, 20000, S1b);
      gemm_mfma<256><<<313, 256, 0, stream>>>(elu_v, DAf, S1b, 1.f/N_V, g1+i*256, be1+i*256,
                                         Wt + (size_t)(2*i+1)*32768, bl1+i*128, nullptr,
                                         v_raw, v_raw, elu_v,
                                         st+(size_t)(2*(i+1))*512, nullptr, N_V);
    } else {
      float* S0  = st + (size_t)(2*i)*512;
      float* S1b = st + (size_t)(2*i+1)*512;
      float* elu_x1 = Dv;
      gemm_mfma<128><<<313, 256, 0, stream>>>(elu_v, nullptr, S0, 1.f/N_V, g0+i*256, be0+i*256,
                                         Wt + (size_t)(2*i)*32768, b0+i*128, oddb+i*256,
                                         nullptr, nullptr, elu_x1,
                                         S1b, nullptr, N_V);
      float* stE = (i==LAYERS-1) ? nullptr : st+(size_t)(2*i+3)*512;
      float* stR = (i==LAYERS-1) ? st+(size_t)62*512 : nullptr;
      gemm_mfma<128><<<313, 256, 0, stream>>>(elu_x1, nullptr, S1b, 1.f/N_V, g1+i*256, be1+i*256,
                                         Wt + (size_t)(2*i+1)*32768, bl1+i*128, oddb+i*256+128,
                                         v_raw, v_raw, elu_v,
                                         stE, stR, N_V);
    }
  }
  final_kernel<<<2500, 256, 0, stream>>>(v_raw, st+(size_t)62*512, g2, be2, W_out, b_out,
                                         (float*)d_out);
}

// Round 8
// 2781.415 us; speedup vs baseline: 1.1226x; 1.1226x over previous
//
#include <hip/hip_runtime.h>
#include <math.h>

#define N_V 5000
#define N_F 10000
#define NNZ 480000
#define LAYERS 30

typedef short short8 __attribute__((ext_vector_type(8)));
typedef float f32x4 __attribute__((ext_vector_type(4)));
union BFu { uint4 u; short8 s8; short s[8]; };

__device__ __forceinline__ float eluf(float x){ return x>0.f ? x : expm1f(x); }
__device__ __forceinline__ short f2bf(float f){
  unsigned u = __float_as_uint(f);
  unsigned r = (u + 0x7fffu + ((u>>16)&1u)) >> 16;
  return (short)r;
}

// ---------------- CSR build ----------------
__global__ void hist_both(const int* __restrict__ Di_rows, const int* __restrict__ DiA_rows,
                          int* __restrict__ Di_cur, int* __restrict__ DA_cur){
  int e = blockIdx.x*256 + threadIdx.x;
  if(e < NNZ){
    atomicAdd(&Di_cur[Di_rows[e]], 1);
    atomicAdd(&DA_cur[DiA_rows[e]], 1);
  }
}

__global__ void chunkscan(const int* __restrict__ Di_cur, int* __restrict__ Di_ptr,
                          const int* __restrict__ DA_cur, int* __restrict__ DA_ptr,
                          int* __restrict__ bsumDi, int* __restrict__ bsumDA){
  __shared__ int ish[256];
  int b = blockIdx.x, tid = threadIdx.x;
  const int nchDi = 157;
  const int* hist; int* optr; int n; int cb; int* bs;
  if(b < nchDi){ hist=Di_cur; optr=Di_ptr; n=40000; cb=b; bs=bsumDi; }
  else { hist=DA_cur; optr=DA_ptr; n=20000; cb=b-nchDi; bs=bsumDA; }
  int i = cb*256 + tid;
  int v = (i<n)? hist[i] : 0;
  ish[tid]=v; __syncthreads();
  for(int off=1; off<256; off<<=1){
    int t = (tid>=off)? ish[tid-off] : 0;
    __syncthreads(); ish[tid]+=t; __syncthreads();
  }
  if(i<n) optr[i] = ish[tid]-v;
  if(tid==255) bs[cb]=ish[255];
}

__global__ void topscan(int* __restrict__ bsumDi, int* __restrict__ bsumDA){
  __shared__ int ish[256];
  int tid=threadIdx.x;
  int* bs = (blockIdx.x==0) ? bsumDi : bsumDA;
  int n  = (blockIdx.x==0) ? 157 : 79;
  int v = (tid<n)? bs[tid] : 0;
  ish[tid]=v; __syncthreads();
  for(int off=1; off<256; off<<=1){
    int t=(tid>=off)? ish[tid-off]:0;
    __syncthreads(); ish[tid]+=t; __syncthreads();
  }
  if(tid<n) bs[tid]=ish[tid]-v;
}

__global__ void addback(int* __restrict__ Di_ptr, int* __restrict__ Di_cur,
                        const int* __restrict__ bsumDi,
                        int* __restrict__ DA_ptr, int* __restrict__ DA_cur,
                        const int* __restrict__ bsumDA){
  int stride = gridDim.x*256;
  int base = blockIdx.x*256 + threadIdx.x;
  for(int i=base;i<40000;i+=stride){ int v=Di_ptr[i]+bsumDi[i>>8]; Di_ptr[i]=v; Di_cur[i]=v; }
  for(int i=base;i<20000;i+=stride){ int v=DA_ptr[i]+bsumDA[i>>8]; DA_ptr[i]=v; DA_cur[i]=v; }
  if(base==0){ Di_ptr[40000]=NNZ; DA_ptr[20000]=NNZ; }
}

// scatter packed (col,val) pairs directly into CSR order
__global__ void scatter_pairs(const int* __restrict__ Di_rows, int* __restrict__ Di_cur,
                              const int* __restrict__ Di_cols, const float* __restrict__ Di_vals,
                              float2* __restrict__ Di_pairs,
                              const int* __restrict__ DiA_rows, int* __restrict__ DA_cur,
                              const int* __restrict__ DiA_cols, const float* __restrict__ DiA_vals,
                              float2* __restrict__ DA_pairs){
  int e = blockIdx.x*256 + threadIdx.x;
  if(e >= NNZ) return;
  int pos = atomicAdd(&Di_cur[Di_rows[e]], 1);
  Di_pairs[pos] = make_float2(__int_as_float(Di_cols[e]), Di_vals[e]);
  pos = atomicAdd(&DA_cur[DiA_rows[e]], 1);
  DA_pairs[pos] = make_float2(__int_as_float(DiA_cols[e]), DiA_vals[e]);
}

// ---------------- weight convert: Wt[(2i+m)*128 + n][k] = bf16(W_m[i][k][n]) ----
__global__ void wconv(const float* __restrict__ W0, const float* __restrict__ Wl1,
                      short* __restrict__ Wt){
  int b = blockIdx.x;            // 60 = i*2+m
  int i = b>>1, m = b&1;
  const float* W = (m ? Wl1 : W0) + (size_t)i*32768;
  short* out = Wt + (size_t)b*32768;
  int k = threadIdx.x;           // 256
  for(int n=0;n<128;++n)
    out[n*256 + k] = f2bf(W[k*128 + n]);
}

// ---------------- conv1 (+ elu stats) + odd-bias precompute ----
__global__ void conv1_kernel(const float* __restrict__ in, const float* __restrict__ W_in,
                             const float* __restrict__ b_in,
                             const float* __restrict__ be0, const float* __restrict__ W0,
                             const float* __restrict__ be1, const float* __restrict__ Wl1,
                             float* __restrict__ v_raw, float* __restrict__ elu_v,
                             float* __restrict__ st1, float* __restrict__ oddb){
  __shared__ float pool[256];
  int tid = threadIdx.x;
  int stride = gridDim.x*256;
  float ls=0.f, ls2=0.f;
  for(int idx = blockIdx.x*256+tid; idx < N_V*128; idx += stride){
    int n = idx>>7, c = idx&127;
    float v = b_in[c] + in[n*3]*W_in[c] + in[n*3+1]*W_in[128+c] + in[n*3+2]*W_in[256+c];
    v_raw[idx] = v;
    float ev = eluf(v);
    elu_v[idx] = ev;
    ls += ev; ls2 += ev*ev;
  }
  int ch = tid & 127;
  pool[tid]=ls; __syncthreads();
  if(tid<128) atomicAdd(&st1[ch], pool[tid]+pool[tid+128]);
  __syncthreads();
  pool[tid]=ls2; __syncthreads();
  if(tid<128) atomicAdd(&st1[256+ch], pool[tid]+pool[tid+128]);
  for(int item = blockIdx.x*256+tid; item < LAYERS*2*128; item += stride){
    int i = item >> 8;
    int m = (item >> 7) & 1;
    int j = item & 127;
    const float* be = m ? be1 : be0;
    const float* W  = m ? Wl1 : W0;
    const float* wp = W + (size_t)i*32768 + 128*128 + j;
    const float* bp = be + i*256 + 128;
    float s = 0.f;
    for(int k=0;k<128;++k) s += bp[k]*wp[k*128];
    oddb[item] = s;
  }
}

// ---------------- SpMM: one wave per row; 8 edge-slots x 8 lane-groups x float4 ----
// 16 edges in flight per iteration; x gathered 16B/lane. Fused channel stats.
__global__ __launch_bounds__(256) void spmm_bn(
    const int* __restrict__ ptr, const float2* __restrict__ pairs,
    const float* __restrict__ x, float* __restrict__ y, int nrows,
    float* __restrict__ stslot){
  __shared__ float pool[128];
  int tid = threadIdx.x;
  int w = tid>>6, lane = tid&63;
  int slot = lane>>3, jg = lane&7;     // 8 edge slots, 8 channel groups (4 ch each)
  float4 ls = make_float4(0,0,0,0), ls2 = make_float4(0,0,0,0);
  for(int row = blockIdx.x*4 + w; row < nrows; row += gridDim.x*4){
    int s = ptr[row], e = ptr[row+1];
    float4 acc = make_float4(0,0,0,0);
    for(int i = s; i < e; i += 16){
      int i0 = i + slot, i1 = i + 8 + slot;
      float2 p0, p1;
      bool b0 = i0 < e, b1 = i1 < e;
      if(b0) p0 = pairs[i0];
      if(b1) p1 = pairs[i1];
      if(b0){
        float4 xv = *(const float4*)&x[(__float_as_int(p0.x)<<5) + jg*4];
        acc.x += p0.y*xv.x; acc.y += p0.y*xv.y; acc.z += p0.y*xv.z; acc.w += p0.y*xv.w;
      }
      if(b1){
        float4 xv = *(const float4*)&x[(__float_as_int(p1.x)<<5) + jg*4];
        acc.x += p1.y*xv.x; acc.y += p1.y*xv.y; acc.z += p1.y*xv.z; acc.w += p1.y*xv.w;
      }
    }
    #pragma unroll
    for(int m = 8; m <= 32; m <<= 1){
      acc.x += __shfl_xor(acc.x, m);
      acc.y += __shfl_xor(acc.y, m);
      acc.z += __shfl_xor(acc.z, m);
      acc.w += __shfl_xor(acc.w, m);
    }
    if(slot == 0){
      *(float4*)&y[(row<<5) + jg*4] = acc;
      ls.x += acc.x; ls.y += acc.y; ls.z += acc.z; ls.w += acc.w;
      ls2.x += acc.x*acc.x; ls2.y += acc.y*acc.y; ls2.z += acc.z*acc.z; ls2.w += acc.w*acc.w;
    }
  }
  // channel base = ((row&3)<<5)|jg*4 = (w<<5)|jg*4  (grid stride multiple of 4 rows)
  if(slot==0) *(float4*)&pool[(w<<5) + jg*4] = ls;
  __syncthreads();
  if(tid<128) atomicAdd(&stslot[128+tid], pool[tid]);
  __syncthreads();
  if(slot==0) *(float4*)&pool[(w<<5) + jg*4] = ls2;
  __syncthreads();
  if(tid<128) atomicAdd(&stslot[384+tid], pool[tid]);
}

// ---------------- MFMA GEMM (R6-proven runtime-K version) ----
// Block 256 thr = 4 waves. Tile 16 rows x 128 cols: wave w -> cols w*32..w*32+31.
// A frag: m=lane&15, k=quad*8+j (fp32 global load + BN + bf16 cvt, no LDS).
// B frag: n=lane&15, k=quad*8+j (16B load from bf16 transposed Wt[n][k], stride 256).
// D frag: col=lane&15, row=quad*4+reg.
__global__ __launch_bounds__(256) void gemm_mfma(
    const float* __restrict__ A0, const float* __restrict__ A1,
    const float* __restrict__ st, float invM,
    const float* __restrict__ g, const float* __restrict__ be,
    const short* __restrict__ Wt, const float* __restrict__ bias,
    const float* __restrict__ bias2, const float* __restrict__ resid,
    float* __restrict__ out_raw, float* __restrict__ out_elu,
    float* __restrict__ stE, float* __restrict__ stR, int M, int K)
{
  __shared__ float ab[256], bb[256];
  int tid = threadIdx.x;
  if(tid < K){
    float mean = st[tid]*invM;
    float var  = fmaxf(st[256+tid]*invM - mean*mean, 0.f);
    float aa   = g[tid]*rsqrtf(var + 1e-5f);
    ab[tid] = aa; bb[tid] = be[tid] - mean*aa;
  }
  __syncthreads();

  int wave = tid>>6, lane = tid&63;
  int ln = lane&15, q = lane>>4;
  int r0 = blockIdx.x*16;
  int c0 = wave*32;
  int kq = q*8;
  int arow = r0 + ln;
  bool aok = arow < M;

  f32x4 acc[2] = {};
  for(int kb=0; kb<K; kb+=32){
    int kg = kb + kq;
    const float* src = A0; int kk = kg;
    if(A1 && kg >= 128){ src = A1; kk = kg - 128; }
    float av[8];
    if(aok){
      float4 x0 = *(const float4*)&src[arow*128 + kk];
      float4 x1 = *(const float4*)&src[arow*128 + kk + 4];
      av[0]=x0.x; av[1]=x0.y; av[2]=x0.z; av[3]=x0.w;
      av[4]=x1.x; av[5]=x1.y; av[6]=x1.z; av[7]=x1.w;
    } else {
      #pragma unroll
      for(int j2=0;j2<8;++j2) av[j2]=0.f;
    }
    BFu af;
    #pragma unroll
    for(int j2=0;j2<8;++j2) af.s[j2] = f2bf(fmaf(av[j2], ab[kg+j2], bb[kg+j2]));
    #pragma unroll
    for(int nb=0;nb<2;++nb){
      int n = c0 + nb*16 + ln;
      BFu bfv; bfv.u = *(const uint4*)&Wt[n*256 + kb + kq];
      acc[nb] = __builtin_amdgcn_mfma_f32_16x16x32_bf16(af.s8, bfv.s8, acc[nb], 0, 0, 0);
    }
  }

  int rbase = r0 + q*4;
  bool wantR = (stR != nullptr);
  #pragma unroll
  for(int nb=0;nb<2;++nb){
    int col = c0 + nb*16 + ln;
    float bsum = bias[col] + (bias2 ? bias2[col] : 0.f);
    float s=0.f, s2=0.f, rs=0.f, rs2=0.f;
    #pragma unroll
    for(int reg=0;reg<4;++reg){
      int row = rbase + reg;
      bool ok = row < M;
      float v = acc[nb][reg] + bsum;
      if(resid && ok) v += resid[row*128 + col];
      float ve = eluf(v);
      if(ok){
        if(out_raw) out_raw[row*128 + col] = v;
        if(out_elu) out_elu[row*128 + col] = ve;
        s += ve; s2 += ve*ve;
        if(wantR){ rs += v; rs2 += v*v; }
      }
    }
    s  += __shfl_xor(s, 16);  s  += __shfl_xor(s, 32);
    s2 += __shfl_xor(s2, 16); s2 += __shfl_xor(s2, 32);
    if(wantR){
      rs  += __shfl_xor(rs, 16);  rs  += __shfl_xor(rs, 32);
      rs2 += __shfl_xor(rs2, 16); rs2 += __shfl_xor(rs2, 32);
    }
    if(q==0){
      if(stE){ atomicAdd(&stE[col], s); atomicAdd(&stE[256+col], s2); }
      if(wantR){ atomicAdd(&stR[col], rs); atomicAdd(&stR[256+col], rs2); }
    }
  }
}

// ---------------- final: BN(v) @ W_out + b_out, elu ------------------
__global__ void final_kernel(const float* __restrict__ v_raw, const float* __restrict__ st,
                             const float* __restrict__ g2, const float* __restrict__ be2,
                             const float* __restrict__ W_out, const float* __restrict__ b_out,
                             float* __restrict__ out){
  __shared__ float pool[256];
  int tid = threadIdx.x; int half = tid>>7, k = tid&127;
  float mean = st[k]*(1.f/N_V);
  float var = fmaxf(st[256+k]*(1.f/N_V) - mean*mean, 0.f);
  float aa = g2[k]*rsqrtf(var+1e-5f);
  float scale = aa*W_out[k];
  float cons = (be2[k]-mean*aa)*W_out[k];
  int r = blockIdx.x*2 + half;
  float val = v_raw[r*128+k]*scale + cons;
  pool[tid]=val; __syncthreads();
  for(int s=64;s>=1;s>>=1){ if(k<s) pool[tid]+=pool[tid+s]; __syncthreads(); }
  if(k==0) out[r] = eluf(pool[tid] + b_out[0]);
}

extern "C" void kernel_launch(void* const* d_in, const int* in_sizes, int n_in,
                              void* d_out, int out_size, void* d_ws, size_t ws_size,
                              hipStream_t stream){
  const float* inputs  = (const float*)d_in[0];
  const int*   Di_rows = (const int*)d_in[2];
  const int*   Di_cols = (const int*)d_in[3];
  const float* Di_vals = (const float*)d_in[4];
  const int*   DiA_rows= (const int*)d_in[5];
  const int*   DiA_cols= (const int*)d_in[6];
  const float* DiA_vals= (const float*)d_in[7];
  const float* W_in = (const float*)d_in[8];  const float* b_in = (const float*)d_in[9];
  const float* g0  = (const float*)d_in[10];  const float* be0 = (const float*)d_in[11];
  const float* W0  = (const float*)d_in[12];  const float* b0  = (const float*)d_in[13];
  const float* g1  = (const float*)d_in[14];  const float* be1 = (const float*)d_in[15];
  const float* Wl1 = (const float*)d_in[16];  const float* bl1 = (const float*)d_in[17];
  const float* g2  = (const float*)d_in[18];  const float* be2 = (const float*)d_in[19];
  const float* W_out = (const float*)d_in[20]; const float* b_out = (const float*)d_in[21];

  float* ws = (float*)d_ws;
  float* v_raw = ws;                       // 640000
  float* elu_v = ws + 640000;              // 640000
  float* elu_f = ws + 1280000;             // 1280000
  float* Dv    = ws + 2560000;             // 1280000 (elu_x1 alias on odd layers)
  float* DAf   = ws + 3840000;             // 640000
  float* st    = ws + 4480000;             // 64*512
  float* oddb  = ws + 4512768;             // 7680
  int* Di_ptr  = (int*)(ws + 4520448);     // 40001
  int* DA_ptr  = (int*)(ws + 4560449);     // 20001
  int* Di_cur  = (int*)(ws + 4580450);     // 40000 } one memset
  int* DA_cur  = (int*)(ws + 4620450);     // 20000 }
  float2* Di_pairs = (float2*)(ws + 4640450);  // 960000 floats (offset even -> 8B aligned)
  float2* DA_pairs = (float2*)(ws + 5600450);  // 960000 floats
  int* bsumDi  = (int*)(ws + 6560450);     // 256
  int* bsumDA  = (int*)(ws + 6560706);     // 128
  short* Wt    = (short*)(ws + 6560834);   // 60*32768 shorts = 983040 floats

  hipMemsetAsync(st, 0, (size_t)64*512*sizeof(float), stream);
  hipMemsetAsync(elu_f, 0, (size_t)1280000*sizeof(float), stream);
  hipMemsetAsync(Di_cur, 0, (size_t)60000*sizeof(int), stream);

  hist_both<<<1875, 256, 0, stream>>>(Di_rows, DiA_rows, Di_cur, DA_cur);
  chunkscan<<<236, 256, 0, stream>>>(Di_cur, Di_ptr, DA_cur, DA_ptr, bsumDi, bsumDA);
  topscan<<<2, 256, 0, stream>>>(bsumDi, bsumDA);
  addback<<<236, 256, 0, stream>>>(Di_ptr, Di_cur, bsumDi, DA_ptr, DA_cur, bsumDA);
  scatter_pairs<<<1875, 256, 0, stream>>>(Di_rows, Di_cur, Di_cols, Di_vals, Di_pairs,
                                          DiA_rows, DA_cur, DiA_cols, DiA_vals, DA_pairs);
  wconv<<<60, 256, 0, stream>>>(W0, Wl1, Wt);
  conv1_kernel<<<640, 256, 0, stream>>>(inputs, W_in, b_in, be0, W0, be1, Wl1,
                                        v_raw, elu_v, st + 512, oddb);

  for(int i=0;i<LAYERS;++i){
    if((i&1)==0){
      float* S0  = st + (size_t)(2*i)*512;
      float* S1b = st + (size_t)(2*i+1)*512;
      spmm_bn<<<2048, 256, 0, stream>>>(Di_ptr, Di_pairs, elu_v, Dv, 40000, S0);
      gemm_mfma<<<625, 256, 0, stream>>>(elu_f, Dv, S0, 1.f/N_F, g0+i*256, be0+i*256,
                                         Wt + (size_t)(2*i)*32768, b0+i*128, nullptr,
                                         nullptr, nullptr, elu_f,
                                         st+(size_t)(2*(i+2))*512, nullptr, N_F, 256);
      spmm_bn<<<1024, 256, 0, stream>>>(DA_ptr, DA_pairs, elu_f, DAf, 20000, S1b);
      gemm_mfma<<<313, 256, 0, stream>>>(elu_v, DAf, S1b, 1.f/N_V, g1+i*256, be1+i*256,
                                         Wt + (size_t)(2*i+1)*32768, bl1+i*128, nullptr,
                                         v_raw, v_raw, elu_v,
                                         st+(size_t)(2*(i+1))*512, nullptr, N_V, 256);
    } else {
      float* S0  = st + (size_t)(2*i)*512;
      float* S1b = st + (size_t)(2*i+1)*512;
      float* elu_x1 = Dv;
      gemm_mfma<<<313, 256, 0, stream>>>(elu_v, nullptr, S0, 1.f/N_V, g0+i*256, be0+i*256,
                                         Wt + (size_t)(2*i)*32768, b0+i*128, oddb+i*256,
                                         nullptr, nullptr, elu_x1,
                                         S1b, nullptr, N_V, 128);
      float* stE = (i==LAYERS-1) ? nullptr : st+(size_t)(2*i+3)*512;
      float* stR = (i==LAYERS-1) ? st+(size_t)62*512 : nullptr;
      gemm_mfma<<<313, 256, 0, stream>>>(elu_x1, nullptr, S1b, 1.f/N_V, g1+i*256, be1+i*256,
                                         Wt + (size_t)(2*i+1)*32768, bl1+i*128, oddb+i*256+128,
                                         v_raw, v_raw, elu_v,
                                         stE, stR, N_V, 128);
    }
  }
  final_kernel<<<2500, 256, 0, stream>>>(v_raw, st+(size_t)62*512, g2, be2, W_out, b_out,
                                         (float*)d_out);
}

// Round 9
// 2736.594 us; speedup vs baseline: 1.1410x; 1.0164x over previous
//
#include <hip/hip_runtime.h>
#include <math.h>

#define N_V 5000
#define N_F 10000
#define NNZ 480000
#define LAYERS 30

typedef short short8 __attribute__((ext_vector_type(8)));
typedef float f32x4 __attribute__((ext_vector_type(4)));
union BFu { uint4 u; short8 s8; short s[8]; unsigned short us[8]; };

__device__ __forceinline__ float eluf(float x){ return x>0.f ? x : expm1f(x); }
__device__ __forceinline__ unsigned short f2bf(float f){
  unsigned u = __float_as_uint(f);
  unsigned r = (u + 0x7fffu + ((u>>16)&1u)) >> 16;
  return (unsigned short)r;
}
__device__ __forceinline__ float bf2f(unsigned short u){
  return __uint_as_float((unsigned)u << 16);
}

// ---------------- CSR build ----------------
__global__ void hist_both(const int* __restrict__ Di_rows, const int* __restrict__ DiA_rows,
                          int* __restrict__ Di_cur, int* __restrict__ DA_cur){
  int e = blockIdx.x*256 + threadIdx.x;
  if(e < NNZ){
    atomicAdd(&Di_cur[Di_rows[e]], 1);
    atomicAdd(&DA_cur[DiA_rows[e]], 1);
  }
}

__global__ void chunkscan(const int* __restrict__ Di_cur, int* __restrict__ Di_ptr,
                          const int* __restrict__ DA_cur, int* __restrict__ DA_ptr,
                          int* __restrict__ bsumDi, int* __restrict__ bsumDA){
  __shared__ int ish[256];
  int b = blockIdx.x, tid = threadIdx.x;
  const int nchDi = 157;
  const int* hist; int* optr; int n; int cb; int* bs;
  if(b < nchDi){ hist=Di_cur; optr=Di_ptr; n=40000; cb=b; bs=bsumDi; }
  else { hist=DA_cur; optr=DA_ptr; n=20000; cb=b-nchDi; bs=bsumDA; }
  int i = cb*256 + tid;
  int v = (i<n)? hist[i] : 0;
  ish[tid]=v; __syncthreads();
  for(int off=1; off<256; off<<=1){
    int t = (tid>=off)? ish[tid-off] : 0;
    __syncthreads(); ish[tid]+=t; __syncthreads();
  }
  if(i<n) optr[i] = ish[tid]-v;
  if(tid==255) bs[cb]=ish[255];
}

__global__ void topscan(int* __restrict__ bsumDi, int* __restrict__ bsumDA){
  __shared__ int ish[256];
  int tid=threadIdx.x;
  int* bs = (blockIdx.x==0) ? bsumDi : bsumDA;
  int n  = (blockIdx.x==0) ? 157 : 79;
  int v = (tid<n)? bs[tid] : 0;
  ish[tid]=v; __syncthreads();
  for(int off=1; off<256; off<<=1){
    int t=(tid>=off)? ish[tid-off]:0;
    __syncthreads(); ish[tid]+=t; __syncthreads();
  }
  if(tid<n) bs[tid]=ish[tid]-v;
}

__global__ void addback(int* __restrict__ Di_ptr, int* __restrict__ Di_cur,
                        const int* __restrict__ bsumDi,
                        int* __restrict__ DA_ptr, int* __restrict__ DA_cur,
                        const int* __restrict__ bsumDA){
  int stride = gridDim.x*256;
  int base = blockIdx.x*256 + threadIdx.x;
  for(int i=base;i<40000;i+=stride){ int v=Di_ptr[i]+bsumDi[i>>8]; Di_ptr[i]=v; Di_cur[i]=v; }
  for(int i=base;i<20000;i+=stride){ int v=DA_ptr[i]+bsumDA[i>>8]; DA_ptr[i]=v; DA_cur[i]=v; }
  if(base==0){ Di_ptr[40000]=NNZ; DA_ptr[20000]=NNZ; }
}

__global__ void scatter_pairs(const int* __restrict__ Di_rows, int* __restrict__ Di_cur,
                              const int* __restrict__ Di_cols, const float* __restrict__ Di_vals,
                              float2* __restrict__ Di_pairs,
                              const int* __restrict__ DiA_rows, int* __restrict__ DA_cur,
                              const int* __restrict__ DiA_cols, const float* __restrict__ DiA_vals,
                              float2* __restrict__ DA_pairs){
  int e = blockIdx.x*256 + threadIdx.x;
  if(e >= NNZ) return;
  int pos = atomicAdd(&Di_cur[Di_rows[e]], 1);
  Di_pairs[pos] = make_float2(__int_as_float(Di_cols[e]), Di_vals[e]);
  pos = atomicAdd(&DA_cur[DiA_rows[e]], 1);
  DA_pairs[pos] = make_float2(__int_as_float(DiA_cols[e]), DiA_vals[e]);
}

// ---------------- weight convert: Wt[(2i+m)*128 + n][k] = bf16(W_m[i][k][n]) ----
__global__ void wconv(const float* __restrict__ W0, const float* __restrict__ Wl1,
                      unsigned short* __restrict__ Wt){
  int b = blockIdx.x;            // 60 = i*2+m
  int i = b>>1, m = b&1;
  const float* W = (m ? Wl1 : W0) + (size_t)i*32768;
  unsigned short* out = Wt + (size_t)b*32768;
  int k = threadIdx.x;           // 256
  for(int n=0;n<128;++n)
    out[n*256 + k] = f2bf(W[k*128 + n]);
}

// ---------------- conv1 (+ elu stats) + odd-bias precompute ----
__global__ void conv1_kernel(const float* __restrict__ in, const float* __restrict__ W_in,
                             const float* __restrict__ b_in,
                             const float* __restrict__ be0, const float* __restrict__ W0,
                             const float* __restrict__ be1, const float* __restrict__ Wl1,
                             float* __restrict__ v_raw, unsigned short* __restrict__ elu_v,
                             float* __restrict__ st1, float* __restrict__ oddb){
  __shared__ float pool[256];
  int tid = threadIdx.x;
  int stride = gridDim.x*256;
  float ls=0.f, ls2=0.f;
  for(int idx = blockIdx.x*256+tid; idx < N_V*128; idx += stride){
    int n = idx>>7, c = idx&127;
    float v = b_in[c] + in[n*3]*W_in[c] + in[n*3+1]*W_in[128+c] + in[n*3+2]*W_in[256+c];
    v_raw[idx] = v;
    float ev = eluf(v);
    elu_v[idx] = f2bf(ev);
    ls += ev; ls2 += ev*ev;
  }
  int ch = tid & 127;
  pool[tid]=ls; __syncthreads();
  if(tid<128) atomicAdd(&st1[ch], pool[tid]+pool[tid+128]);
  __syncthreads();
  pool[tid]=ls2; __syncthreads();
  if(tid<128) atomicAdd(&st1[256+ch], pool[tid]+pool[tid+128]);
  for(int item = blockIdx.x*256+tid; item < LAYERS*2*128; item += stride){
    int i = item >> 8;
    int m = (item >> 7) & 1;
    int j = item & 127;
    const float* be = m ? be1 : be0;
    const float* W  = m ? Wl1 : W0;
    const float* wp = W + (size_t)i*32768 + 128*128 + j;
    const float* bp = be + i*256 + 128;
    float s = 0.f;
    for(int k=0;k<128;++k) s += bp[k]*wp[k*128];
    oddb[item] = s;
  }
}

// ---------------- SpMM: one wave per row; 8 edge-slots x 8 lane-groups x 4ch ----
// x is bf16 (64B/row): each lane-group loads ushort4 (8B). Fused channel stats.
__global__ __launch_bounds__(256) void spmm_bn(
    const int* __restrict__ ptr, const float2* __restrict__ pairs,
    const unsigned short* __restrict__ x, float* __restrict__ y, int nrows,
    float* __restrict__ stslot){
  __shared__ float pool[128];
  int tid = threadIdx.x;
  int w = tid>>6, lane = tid&63;
  int slot = lane>>3, jg = lane&7;     // 8 edge slots, 8 channel groups (4 ch each)
  float4 ls = make_float4(0,0,0,0), ls2 = make_float4(0,0,0,0);
  for(int row = blockIdx.x*4 + w; row < nrows; row += gridDim.x*4){
    int s = ptr[row], e = ptr[row+1];
    float4 acc = make_float4(0,0,0,0);
    for(int i = s; i < e; i += 16){
      int i0 = i + slot, i1 = i + 8 + slot;
      float2 p0, p1;
      bool b0 = i0 < e, b1 = i1 < e;
      if(b0) p0 = pairs[i0];
      if(b1) p1 = pairs[i1];
      if(b0){
        ushort4 xv = *(const ushort4*)&x[(__float_as_int(p0.x)<<5) + jg*4];
        acc.x += p0.y*bf2f(xv.x); acc.y += p0.y*bf2f(xv.y);
        acc.z += p0.y*bf2f(xv.z); acc.w += p0.y*bf2f(xv.w);
      }
      if(b1){
        ushort4 xv = *(const ushort4*)&x[(__float_as_int(p1.x)<<5) + jg*4];
        acc.x += p1.y*bf2f(xv.x); acc.y += p1.y*bf2f(xv.y);
        acc.z += p1.y*bf2f(xv.z); acc.w += p1.y*bf2f(xv.w);
      }
    }
    #pragma unroll
    for(int m = 8; m <= 32; m <<= 1){
      acc.x += __shfl_xor(acc.x, m);
      acc.y += __shfl_xor(acc.y, m);
      acc.z += __shfl_xor(acc.z, m);
      acc.w += __shfl_xor(acc.w, m);
    }
    if(slot == 0){
      *(float4*)&y[(row<<5) + jg*4] = acc;
      ls.x += acc.x; ls.y += acc.y; ls.z += acc.z; ls.w += acc.w;
      ls2.x += acc.x*acc.x; ls2.y += acc.y*acc.y; ls2.z += acc.z*acc.z; ls2.w += acc.w*acc.w;
    }
  }
  if(slot==0) *(float4*)&pool[(w<<5) + jg*4] = ls;
  __syncthreads();
  if(tid<128) atomicAdd(&stslot[128+tid], pool[tid]);
  __syncthreads();
  if(slot==0) *(float4*)&pool[(w<<5) + jg*4] = ls2;
  __syncthreads();
  if(tid<128) atomicAdd(&stslot[384+tid], pool[tid]);
}

// ---------------- MFMA GEMM: A0 bf16, A1 fp32 (spmm out). ----
// Block 256 thr = 4 waves. Tile 16 rows x 128 cols: wave w -> cols w*32..w*32+31.
// A frag: m=lane&15, k=quad*8+j (global load + BN affine + bf16 cvt, no LDS).
// B frag: n=lane&15, k=quad*8+j (16B load from bf16 transposed Wt[n][k], stride 256).
// D frag: col=lane&15, row=quad*4+reg.
__global__ __launch_bounds__(256) void gemm_mfma(
    const unsigned short* __restrict__ A0, const float* __restrict__ A1,
    const float* __restrict__ st, float invM,
    const float* __restrict__ g, const float* __restrict__ be,
    const unsigned short* __restrict__ Wt, const float* __restrict__ bias,
    const float* __restrict__ bias2, const float* __restrict__ resid,
    float* __restrict__ out_raw, unsigned short* __restrict__ out_elu,
    float* __restrict__ stE, float* __restrict__ stR, int M, int K)
{
  __shared__ float ab[256], bb[256];
  int tid = threadIdx.x;
  if(tid < K){
    float mean = st[tid]*invM;
    float var  = fmaxf(st[256+tid]*invM - mean*mean, 0.f);
    float aa   = g[tid]*rsqrtf(var + 1e-5f);
    ab[tid] = aa; bb[tid] = be[tid] - mean*aa;
  }
  __syncthreads();

  int wave = tid>>6, lane = tid&63;
  int ln = lane&15, q = lane>>4;
  int r0 = blockIdx.x*16;
  int c0 = wave*32;
  int kq = q*8;
  int arow = r0 + ln;
  bool aok = arow < M;

  f32x4 acc[2] = {};
  for(int kb=0; kb<K; kb+=32){
    int kg = kb + kq;
    float av[8];
    if(!aok){
      #pragma unroll
      for(int j2=0;j2<8;++j2) av[j2]=0.f;
    } else if(A1 && kg >= 128){
      int kk = kg - 128;
      float4 x0 = *(const float4*)&A1[arow*128 + kk];
      float4 x1 = *(const float4*)&A1[arow*128 + kk + 4];
      av[0]=x0.x; av[1]=x0.y; av[2]=x0.z; av[3]=x0.w;
      av[4]=x1.x; av[5]=x1.y; av[6]=x1.z; av[7]=x1.w;
    } else {
      BFu raw; raw.u = *(const uint4*)&A0[arow*128 + kg];
      #pragma unroll
      for(int j2=0;j2<8;++j2) av[j2] = bf2f(raw.us[j2]);
    }
    BFu af;
    #pragma unroll
    for(int j2=0;j2<8;++j2) af.us[j2] = f2bf(fmaf(av[j2], ab[kg+j2], bb[kg+j2]));
    #pragma unroll
    for(int nb=0;nb<2;++nb){
      int n = c0 + nb*16 + ln;
      BFu bfv; bfv.u = *(const uint4*)&Wt[n*256 + kb + kq];
      acc[nb] = __builtin_amdgcn_mfma_f32_16x16x32_bf16(af.s8, bfv.s8, acc[nb], 0, 0, 0);
    }
  }

  // all waves' A-reads complete before any in-place elu writes (A0 may alias out_elu)
  __syncthreads();

  int rbase = r0 + q*4;
  bool wantR = (stR != nullptr);
  #pragma unroll
  for(int nb=0;nb<2;++nb){
    int col = c0 + nb*16 + ln;
    float bsum = bias[col] + (bias2 ? bias2[col] : 0.f);
    float s=0.f, s2=0.f, rs=0.f, rs2=0.f;
    #pragma unroll
    for(int reg=0;reg<4;++reg){
      int row = rbase + reg;
      bool ok = row < M;
      float v = acc[nb][reg] + bsum;
      if(resid && ok) v += resid[row*128 + col];
      float ve = eluf(v);
      if(ok){
        if(out_raw) out_raw[row*128 + col] = v;
        if(out_elu) out_elu[row*128 + col] = f2bf(ve);
        s += ve; s2 += ve*ve;
        if(wantR){ rs += v; rs2 += v*v; }
      }
    }
    s  += __shfl_xor(s, 16);  s  += __shfl_xor(s, 32);
    s2 += __shfl_xor(s2, 16); s2 += __shfl_xor(s2, 32);
    if(wantR){
      rs  += __shfl_xor(rs, 16);  rs  += __shfl_xor(rs, 32);
      rs2 += __shfl_xor(rs2, 16); rs2 += __shfl_xor(rs2, 32);
    }
    if(q==0){
      if(stE){ atomicAdd(&stE[col], s); atomicAdd(&stE[256+col], s2); }
      if(wantR){ atomicAdd(&stR[col], rs); atomicAdd(&stR[256+col], rs2); }
    }
  }
}

// ---------------- final: BN(v) @ W_out + b_out, elu ------------------
__global__ void final_kernel(const float* __restrict__ v_raw, const float* __restrict__ st,
                             const float* __restrict__ g2, const float* __restrict__ be2,
                             const float* __restrict__ W_out, const float* __restrict__ b_out,
                             float* __restrict__ out){
  __shared__ float pool[256];
  int tid = threadIdx.x; int half = tid>>7, k = tid&127;
  float mean = st[k]*(1.f/N_V);
  float var = fmaxf(st[256+k]*(1.f/N_V) - mean*mean, 0.f);
  float aa = g2[k]*rsqrtf(var+1e-5f);
  float scale = aa*W_out[k];
  float cons = (be2[k]-mean*aa)*W_out[k];
  int r = blockIdx.x*2 + half;
  float val = v_raw[r*128+k]*scale + cons;
  pool[tid]=val; __syncthreads();
  for(int s=64;s>=1;s>>=1){ if(k<s) pool[tid]+=pool[tid+s]; __syncthreads(); }
  if(k==0) out[r] = eluf(pool[tid] + b_out[0]);
}

extern "C" void kernel_launch(void* const* d_in, const int* in_sizes, int n_in,
                              void* d_out, int out_size, void* d_ws, size_t ws_size,
                              hipStream_t stream){
  const float* inputs  = (const float*)d_in[0];
  const int*   Di_rows = (const int*)d_in[2];
  const int*   Di_cols = (const int*)d_in[3];
  const float* Di_vals = (const float*)d_in[4];
  const int*   DiA_rows= (const int*)d_in[5];
  const int*   DiA_cols= (const int*)d_in[6];
  const float* DiA_vals= (const float*)d_in[7];
  const float* W_in = (const float*)d_in[8];  const float* b_in = (const float*)d_in[9];
  const float* g0  = (const float*)d_in[10];  const float* be0 = (const float*)d_in[11];
  const float* W0  = (const float*)d_in[12];  const float* b0  = (const float*)d_in[13];
  const float* g1  = (const float*)d_in[14];  const float* be1 = (const float*)d_in[15];
  const float* Wl1 = (const float*)d_in[16];  const float* bl1 = (const float*)d_in[17];
  const float* g2  = (const float*)d_in[18];  const float* be2 = (const float*)d_in[19];
  const float* W_out = (const float*)d_in[20]; const float* b_out = (const float*)d_in[21];

  float* ws = (float*)d_ws;
  float* v_raw = ws;                                   // 640000 f
  unsigned short* elu_v = (unsigned short*)(ws + 640000);   // 640000 bf16 (uses half region)
  unsigned short* elu_f = (unsigned short*)(ws + 1280000);  // 1280000 bf16
  float* Dv    = ws + 2560000;             // 1280000 f (elu_x1 alias on odd layers)
  float* DAf   = ws + 3840000;             // 640000 f
  float* st    = ws + 4480000;             // 64*512
  float* oddb  = ws + 4512768;             // 7680
  int* Di_ptr  = (int*)(ws + 4520448);     // 40001
  int* DA_ptr  = (int*)(ws + 4560449);     // 20001
  int* Di_cur  = (int*)(ws + 4580450);     // 40000 } one memset
  int* DA_cur  = (int*)(ws + 4620450);     // 20000 }
  float2* Di_pairs = (float2*)(ws + 4640450);  // 960000 floats (offset even -> 8B aligned)
  float2* DA_pairs = (float2*)(ws + 5600450);  // 960000 floats
  int* bsumDi  = (int*)(ws + 6560450);     // 256
  int* bsumDA  = (int*)(ws + 6560706);     // 128
  unsigned short* Wt = (unsigned short*)(ws + 6560834);  // 60*32768 shorts
  unsigned short* elu_x1 = (unsigned short*)Dv;          // odd layers only

  hipMemsetAsync(st, 0, (size_t)64*512*sizeof(float), stream);
  hipMemsetAsync(elu_f, 0, (size_t)1280000*sizeof(unsigned short), stream);
  hipMemsetAsync(Di_cur, 0, (size_t)60000*sizeof(int), stream);

  hist_both<<<1875, 256, 0, stream>>>(Di_rows, DiA_rows, Di_cur, DA_cur);
  chunkscan<<<236, 256, 0, stream>>>(Di_cur, Di_ptr, DA_cur, DA_ptr, bsumDi, bsumDA);
  topscan<<<2, 256, 0, stream>>>(bsumDi, bsumDA);
  addback<<<236, 256, 0, stream>>>(Di_ptr, Di_cur, bsumDi, DA_ptr, DA_cur, bsumDA);
  scatter_pairs<<<1875, 256, 0, stream>>>(Di_rows, Di_cur, Di_cols, Di_vals, Di_pairs,
                                          DiA_rows, DA_cur, DiA_cols, DiA_vals, DA_pairs);
  wconv<<<60, 256, 0, stream>>>(W0, Wl1, Wt);
  conv1_kernel<<<640, 256, 0, stream>>>(inputs, W_in, b_in, be0, W0, be1, Wl1,
                                        v_raw, elu_v, st + 512, oddb);

  for(int i=0;i<LAYERS;++i){
    if((i&1)==0){
      float* S0  = st + (size_t)(2*i)*512;
      float* S1b = st + (size_t)(2*i+1)*512;
      spmm_bn<<<2048, 256, 0, stream>>>(Di_ptr, Di_pairs, elu_v, Dv, 40000, S0);
      gemm_mfma<<<625, 256, 0, stream>>>(elu_f, Dv, S0, 1.f/N_F, g0+i*256, be0+i*256,
                                         Wt + (size_t)(2*i)*32768, b0+i*128, nullptr,
                                         nullptr, nullptr, elu_f,
                                         st+(size_t)(2*(i+2))*512, nullptr, N_F, 256);
      spmm_bn<<<1024, 256, 0, stream>>>(DA_ptr, DA_pairs, elu_f, DAf, 20000, S1b);
      gemm_mfma<<<313, 256, 0, stream>>>(elu_v, DAf, S1b, 1.f/N_V, g1+i*256, be1+i*256,
                                         Wt + (size_t)(2*i+1)*32768, bl1+i*128, nullptr,
                                         v_raw, v_raw, elu_v,
                                         st+(size_t)(2*(i+1))*512, nullptr, N_V, 256);
    } else {
      float* S0  = st + (size_t)(2*i)*512;
      float* S1b = st + (size_t)(2*i+1)*512;
      gemm_mfma<<<313, 256, 0, stream>>>(elu_v, nullptr, S0, 1.f/N_V, g0+i*256, be0+i*256,
                                         Wt + (size_t)(2*i)*32768, b0+i*128, oddb+i*256,
                                         nullptr, nullptr, elu_x1,
                                         S1b, nullptr, N_V, 128);
      float* stE = (i==LAYERS-1) ? nullptr : st+(size_t)(2*i+3)*512;
      float* stR = (i==LAYERS-1) ? st+(size_t)62*512 : nullptr;
      gemm_mfma<<<313, 256, 0, stream>>>(elu_x1, nullptr, S1b, 1.f/N_V, g1+i*256, be1+i*256,
                                         Wt + (size_t)(2*i+1)*32768, bl1+i*128, oddb+i*256+128,
                                         v_raw, v_raw, elu_v,
                                         stE, stR, N_V, 128);
    }
  }
  final_kernel<<<2500, 256, 0, stream>>>(v_raw, st+(size_t)62*512, g2, be2, W_out, b_out,
                                         (float*)d_out);
}